// Round 5
// baseline (383.295 us; speedup 1.0000x reference)
//
#include <hip/hip_runtime.h>
#include <math.h>

#define TEMPC   0.07f
#define NBK     15
#define HALFK   7
#define NPOS    225      // 15*15
#define DD      128
#define HHH     256
#define WWW     256
#define PLANE   (HHH * WWW)   // 65536
#define NSAMP   256
#define EPSC    1e-8f

#define CCH     32            // channels per staged chunk
#define NCH     (DD / CCH)    // 4
#define GRP     32            // anchors per afl group (ngrp==1 for ncnt<=32)
#define CAPA    128           // anchors per dacc pass (ncnt>128 ~never: mean 15.9)
#define MAXA    256

// ---------------- kernel A: per-anchor prep (feature gather + norm + label) ----
__global__ __launch_bounds__(128) void k_prep(
    const float* __restrict__ feat,
    const int*   __restrict__ targ,
    const int*   __restrict__ anch_h,
    const int*   __restrict__ anch_w,
    float*       __restrict__ afg,
    float*       __restrict__ anorm,
    int*         __restrict__ alab_g)
{
    const int bn = blockIdx.x;
    const int b  = bn >> 8;               // NSAMP == 256
    const int d  = threadIdx.x;           // 0..127
    const int ah = anch_h[bn], aw = anch_w[bn];

    float v = feat[(size_t)b * DD * PLANE + (size_t)d * PLANE + ah * WWW + aw];
    afg[(size_t)bn * DD + d] = v;

    float s = v * v;
    #pragma unroll
    for (int off = 32; off; off >>= 1) s += __shfl_down(s, off, 64);
    __shared__ float r2[2];
    if ((d & 63) == 0) r2[d >> 6] = s;
    __syncthreads();
    if (d == 0) {
        anorm[bn]  = fmaxf(sqrtf(r2[0] + r2[1]), EPSC);
        alab_g[bn] = targ[b * PLANE + ah * WWW + aw];
    }
}

// ---------------- kernel B: image-row sweep ----------------
// block = (image b, row h). Streams the row's 128 channels coalesced exactly
// once. Emits, for every (anchor,patch-row,col) owned by this row (unique
// writer): simn = dot/pn, and pos byte = (label match). No normimg, no
// scattered reads downstream.
__global__ __launch_bounds__(256, 3) void k_sweep(
    const float* __restrict__ feat,
    const int*   __restrict__ anch_h,
    const int*   __restrict__ anch_w,
    const float* __restrict__ afg,
    const int*   __restrict__ alab_g,
    const int*   __restrict__ targ,
    float*       __restrict__ simn,
    unsigned char* __restrict__ posm)
{
    const int bh   = blockIdx.x;
    const int b    = bh >> 8;
    const int h    = bh & 255;
    const int tid  = threadIdx.x;
    const int lane = tid & 63;
    const int wave = tid >> 6;

    __shared__ __align__(16) float rows[CCH][WWW];   // 32 KB
    __shared__ float dacc[CAPA * NBK];               // 7.5 KB
    __shared__ float afl[GRP][CCH + 1];              // 4.2 KB, padded
    __shared__ float pn_s[WWW];                      // 1 KB
    __shared__ int   labs[WWW];                      // 1 KB
    __shared__ int   s_n[MAXA], s_aw[MAXA], s_alab[MAXA], s_k[MAXA]; // 4 KB
    __shared__ int   wcnt[4];

    // ---- build this row's anchor list (ballot compaction) ----
    const int ah_t = anch_h[b * NSAMP + tid];
    const bool in  = (ah_t - h <= HALFK) && (h - ah_t <= HALFK);
    unsigned long long m = __ballot(in);
    if (lane == 0) wcnt[wave] = __popcll(m);
    labs[tid] = targ[b * PLANE + h * WWW + tid];
    __syncthreads();
    const int ncnt = wcnt[0] + wcnt[1] + wcnt[2] + wcnt[3];
    if (in) {
        int base0 = 0;
        #pragma unroll
        for (int w = 0; w < 4; ++w) if (w < wave) base0 += wcnt[w];
        int p = base0 + __popcll(m & ((1ULL << lane) - 1ULL));
        s_n[p]    = tid;
        s_aw[p]   = anch_w[b * NSAMP + tid];
        s_alab[p] = alab_g[b * NSAMP + tid];
        s_k[p]    = h - ah_t + HALFK;
    }
    __syncthreads();
    if (ncnt == 0) return;

    const float* fbh = feat + (size_t)b * DD * PLANE + h * WWW;
    float nrm = 0.f;

    for (int base = 0; base < ncnt; base += CAPA) {
        const int nloc  = min(CAPA, ncnt - base);
        const int nposl = nloc * NBK;
        const int ngrp  = (nloc + GRP - 1) / GRP;
        for (int p = tid; p < nposl; p += 256) dacc[p] = 0.f;

        for (int c = 0; c < NCH; ++c) {
            const int ch0 = c * CCH;
            __syncthreads();   // prev chunk's readers (rows/afl) + dacc zero ordering
            // stage 32 channels x 256 floats, fully coalesced float4
            #pragma unroll
            for (int i = 0; i < 8; ++i) {
                int f  = i * 256 + tid;   // float4 index 0..2047
                int ch = f >> 6;          // 64 float4 per channel row
                int c4 = f & 63;
                *(float4*)&rows[ch][c4 * 4] =
                    *(const float4*)&fbh[(size_t)(ch0 + ch) * PLANE + c4 * 4];
            }
            // anchor-fragment load for group 0 (overlapped with row staging)
            {
                const int na = min(GRP, nloc);
                for (int f = tid; f < na * CCH; f += 256) {
                    int j = f >> 5, cc = f & 31;
                    afl[j][cc] = afg[(size_t)(b * NSAMP + s_n[base + j]) * DD + ch0 + cc];
                }
            }
            __syncthreads();
            if (base == 0) {
                #pragma unroll
                for (int ch = 0; ch < CCH; ++ch) {
                    float v = rows[ch][tid];
                    nrm = fmaf(v, v, nrm);
                }
            }
            for (int g = 0; g < ngrp; ++g) {
                const int a0 = g * GRP;
                const int na = min(GRP, nloc - a0);
                if (g > 0) {
                    __syncthreads();
                    for (int f = tid; f < na * CCH; f += 256) {
                        int j = f >> 5, cc = f & 31;
                        afl[j][cc] = afg[(size_t)(b * NSAMP + s_n[base + a0 + j]) * DD + ch0 + cc];
                    }
                    __syncthreads();
                }
                for (int p = tid; p < na * NBK; p += 256) {
                    int j    = p / NBK;
                    int cpos = p - j * NBK;
                    int col  = s_aw[base + a0 + j] - HALFK + cpos;
                    float dsum = 0.f;
                    #pragma unroll
                    for (int ch = 0; ch < CCH; ++ch)
                        dsum = fmaf(afl[j][ch], rows[ch][col], dsum);
                    dacc[(a0 + j) * NBK + cpos] += dsum;
                }
            }
        }
        if (base == 0) pn_s[tid] = fmaxf(sqrtf(nrm), EPSC);
        __syncthreads();   // dacc complete + pn_s visible

        for (int p = tid; p < nposl; p += 256) {
            int slot = p / NBK;
            int cpos = p - slot * NBK;
            int a    = base + slot;
            int bn   = b * NSAMP + s_n[a];
            int col  = s_aw[a] - HALFK + cpos;
            int o    = bn * NPOS + s_k[a] * NBK + cpos;
            simn[o] = dacc[p] / pn_s[col];
            posm[o] = (labs[col] == s_alab[a]) ? 1 : 0;
        }
        __syncthreads();   // output readers of dacc done before next pass zeroes
    }
}

// ---------------- kernel C: per-anchor softmax / loss (all coalesced) --------
__global__ __launch_bounds__(256) void k_softmax(
    const float*         __restrict__ simn,
    const unsigned char* __restrict__ posm,
    const float*         __restrict__ anorm,
    float*               __restrict__ loss_part,
    float*               __restrict__ cnt_part)
{
    const int bn   = blockIdx.x;
    const int tid  = threadIdx.x;
    const int lane = tid & 63;
    const int wave = tid >> 6;
    __shared__ float red[4], red2[4], red3[4];
    __shared__ float s_max;

    const bool active = tid < NPOS;
    float sim = -INFINITY;
    bool  pos = false;
    if (active) {
        float sc = 1.0f / (anorm[bn] * TEMPC);
        sim = simn[bn * NPOS + tid] * sc;
        pos = posm[bn * NPOS + tid] && (tid != (HALFK * NBK + HALFK));
    }

    float mx = sim;
    #pragma unroll
    for (int off = 32; off; off >>= 1) mx = fmaxf(mx, __shfl_down(mx, off, 64));
    if (lane == 0) red[wave] = mx;
    __syncthreads();
    if (tid == 0) s_max = fmaxf(fmaxf(red[0], red[1]), fmaxf(red[2], red[3]));
    __syncthreads();
    mx = s_max;

    float e  = active ? expf(sim - mx) : 0.f;
    float ps = pos ? sim : 0.f;
    float pc = pos ? 1.f : 0.f;
    #pragma unroll
    for (int off = 32; off; off >>= 1) {
        e  += __shfl_down(e,  off, 64);
        ps += __shfl_down(ps, off, 64);
        pc += __shfl_down(pc, off, 64);
    }
    if (lane == 0) { red[wave] = e; red2[wave] = ps; red3[wave] = pc; }
    __syncthreads();
    if (tid == 0) {
        float E  = red[0]  + red[1]  + red[2]  + red[3];
        float PS = red2[0] + red2[1] + red2[2] + red2[3];
        float PC = red3[0] + red3[1] + red3[2] + red3[3];
        float lse = mx + logf(E);
        bool valid = PC > 0.5f;
        loss_part[bn] = valid ? (lse - PS / PC) : 0.f;
        cnt_part[bn]  = valid ? 1.f : 0.f;
    }
}

// ---------------- kernel D: final reduce ----------------
__global__ __launch_bounds__(256) void lcl_finalize(
    const float* __restrict__ loss_part,
    const float* __restrict__ cnt_part,
    float*       __restrict__ out,
    int n)
{
    const int tid  = threadIdx.x;
    const int lane = tid & 63;
    const int wave = tid >> 6;
    __shared__ float rs[4], rc[4];

    float s = 0.f, c = 0.f;
    for (int i = tid; i < n; i += 256) {
        s += loss_part[i];
        c += cnt_part[i];
    }
    #pragma unroll
    for (int off = 32; off; off >>= 1) {
        s += __shfl_down(s, off, 64);
        c += __shfl_down(c, off, 64);
    }
    if (lane == 0) { rs[wave] = s; rc[wave] = c; }
    __syncthreads();
    if (tid == 0) {
        float S = rs[0] + rs[1] + rs[2] + rs[3];
        float C = rc[0] + rc[1] + rc[2] + rc[3];
        out[0] = (C > 0.5f) ? (S / C) : 0.f;
    }
}

extern "C" void kernel_launch(void* const* d_in, const int* in_sizes, int n_in,
                              void* d_out, int out_size, void* d_ws, size_t ws_size,
                              hipStream_t stream) {
    const float* feat  = (const float*)d_in[0];
    const int*   targ  = (const int*)d_in[1];
    const int*   anchh = (const int*)d_in[2];
    const int*   anchw = (const int*)d_in[3];
    float* out = (float*)d_out;

    const int n_anchors = in_sizes[2];        // B * NUM_SAMPLES = 2048
    const int B = n_anchors / NSAMP;          // 8

    float* afg       = (float*)d_ws;                           // 2048*128
    float* anorm     = afg       + (size_t)n_anchors * DD;     // 2048
    float* simn      = anorm     + n_anchors;                  // 2048*225
    float* loss_part = simn      + (size_t)n_anchors * NPOS;   // 2048
    float* cnt_part  = loss_part + n_anchors;                  // 2048
    int*   alab_g    = (int*)(cnt_part + n_anchors);           // 2048
    unsigned char* posm = (unsigned char*)(alab_g + n_anchors); // 2048*225

    k_prep<<<n_anchors, 128, 0, stream>>>(feat, targ, anchh, anchw,
                                          afg, anorm, alab_g);
    k_sweep<<<B * HHH, 256, 0, stream>>>(feat, anchh, anchw, afg, alab_g, targ,
                                         simn, posm);
    k_softmax<<<n_anchors, 256, 0, stream>>>(simn, posm, anorm,
                                             loss_part, cnt_part);
    lcl_finalize<<<1, 256, 0, stream>>>(loss_part, cnt_part, out, n_anchors);
}